// Round 6
// baseline (58.964 us; speedup 1.0000x reference)
//
#include <hip/hip_runtime.h>

// ViT patch-embed, fused single kernel.
// out[b,0,e] = cls[e] + pos[0,e];  out[b,n+1,e] = sum_k patch[b,n,k]*W[e,k] + pos[n+1,e]
// B=1024, 64 patches of K=48 (padded to 64), E=768. Output 204.5 MB f32.
// R4 lesson: NO nontemporal stores (cost +11.5us; L2 write-back aggregation needed).
// R6: swapped MFMA operands (A=W, B=patches^T) so D rows = embeds -> each lane
// holds 4 consecutive embeds -> dwordx4 stores + dwordx4 pos loads.
// Epilogue VMEM instrs per thread: 192 scalar -> 48 x dwordx4.

#define BATCH   1024
#define EMBED   768
#define NPATCH  64
#define SEQ     65
#define OUTB    (SEQ * EMBED)   // 49920

typedef __attribute__((ext_vector_type(8))) short bf16x8;   // 8 bf16 (4 VGPRs)
typedef __attribute__((ext_vector_type(4))) float f32x4;    // MFMA acc / 16B ld-st

__device__ __forceinline__ short f2bf(float f) {
    union { float f; unsigned u; } v; v.f = f;
    unsigned r = v.u + 0x7FFFu + ((v.u >> 16) & 1u);   // RNE
    return (short)(r >> 16);
}

// ---------------------------------------------------------------------------
// One batch per block, 8 waves. Wave owns 96 embeds (6 M-tiles of 16).
// A-operand = W-tile   (M=16 embeds x K=32): lane -> row e (l&15), k=(l>>4)*8+j
// B-operand = patch^T  (K=32 x N=16 patches): lane -> col n (l&15), k=(l>>4)*8+j
// D: lane -> col n (l&15), row e = (l>>4)*4 + reg  => 4 consecutive embeds/lane.
// Patches (bf16 [64][64], K-padded) in LDS, chunk kb of row r at (kb^(r&7)).
// ---------------------------------------------------------------------------
__global__ __launch_bounds__(512, 4) void patch_embed_fused(const float* __restrict__ x,
                                                            const float* __restrict__ W,
                                                            const float* __restrict__ cls,
                                                            const float* __restrict__ pos,
                                                            float* __restrict__ out) {
    __shared__ short A[64 * 64];   // 8 KB

    const int tid  = threadIdx.x;
    const int lane = tid & 63;
    const int wave = tid >> 6;     // 0..7
    const int lr   = lane & 15;
    const int lg   = lane >> 4;    // 0..3
    const int ebase = wave * 96;
    const int b = blockIdx.x;

    // ---- cls row: out[b,0,:] = cls + pos[0,:]  (192 float4, threads 0..191) ----
    if (tid < 192) {
        f32x4 cv = ((const f32x4*)cls)[tid];
        f32x4 pv = ((const f32x4*)pos)[tid];
        f32x4 o = cv + pv;
        ((f32x4*)out)[(size_t)b * (OUTB / 4) + tid] = o;
    }

    // ---- stage x[b] -> LDS bf16 patches [64][64], swizzled 16B chunks ----
    {
        const int row = tid >> 3;            // patch n = gr*8+gc
        const int kb  = tid & 7;             // 8-bf16 chunk within the 64-wide row
        short* dst = &A[row * 64 + ((kb ^ (row & 7)) * 8)];
        bf16x8 v = {0, 0, 0, 0, 0, 0, 0, 0};
        if (kb < 6) {   // k = c*16 + ph*4 + pw
            const int c   = kb >> 1;
            const int ph0 = (kb & 1) * 2;
            const int gr = row >> 3, gc = row & 7;
            const float* src = x + (size_t)b * 3072 + c * 1024 + (gr * 4 + ph0) * 32 + gc * 4;
            float4 u0 = *(const float4*)src;
            float4 u1 = *(const float4*)(src + 32);
            v[0] = f2bf(u0.x); v[1] = f2bf(u0.y); v[2] = f2bf(u0.z); v[3] = f2bf(u0.w);
            v[4] = f2bf(u1.x); v[5] = f2bf(u1.y); v[6] = f2bf(u1.z); v[7] = f2bf(u1.w);
        }
        *(bf16x8*)dst = v;
    }

    // ---- W fragments (A-operand) -> registers: aw[6][2], 48 VGPR ----
    // lane holds W row (ebase + et*16 + lr), k = kk*32 + lg*8 + j
    bf16x8 aw[6][2];
    #pragma unroll
    for (int et = 0; et < 6; ++et) {
        const float* wrow = W + (ebase + et * 16 + lr) * 48;
        #pragma unroll
        for (int kk = 0; kk < 2; ++kk) {
            const int k0 = kk * 32 + lg * 8;
            bf16x8 f = {0, 0, 0, 0, 0, 0, 0, 0};
            if (k0 < 48) {
                float4 u0 = *(const float4*)(wrow + k0);
                float4 u1 = *(const float4*)(wrow + k0 + 4);
                f[0] = f2bf(u0.x); f[1] = f2bf(u0.y); f[2] = f2bf(u0.z); f[3] = f2bf(u0.w);
                f[4] = f2bf(u1.x); f[5] = f2bf(u1.y); f[6] = f2bf(u1.z); f[7] = f2bf(u1.w);
            }
            aw[et][kk] = f;
        }
    }

    __syncthreads();

    // ---- compute + vectorized epilogue, one patch N-tile (16 patches) at a time ----
    const size_t outbase = (size_t)b * OUTB + EMBED;   // rows n=1..64
    const f32x4 zero = {0.f, 0.f, 0.f, 0.f};
    #pragma unroll 1
    for (int pt = 0; pt < 4; ++pt) {
        const int prow = pt * 16 + lr;     // this lane's patch (B col / D col)
        const int sw0  = ((0 * 4 + lg) ^ (prow & 7)) * 8;
        const int sw1  = ((1 * 4 + lg) ^ (prow & 7)) * 8;
        bf16x8 p0 = *(const bf16x8*)&A[prow * 64 + sw0];   // k 0..31
        bf16x8 p1 = *(const bf16x8*)&A[prow * 64 + sw1];   // k 32..63

        const float* posrow = pos + (size_t)(prow + 1) * EMBED;
        float*       orow   = out + outbase + (size_t)prow * EMBED;

        #pragma unroll
        for (int et = 0; et < 6; ++et) {
            f32x4 acc = __builtin_amdgcn_mfma_f32_16x16x32_bf16(aw[et][0], p0, zero, 0, 0, 0);
            acc = __builtin_amdgcn_mfma_f32_16x16x32_bf16(aw[et][1], p1, acc, 0, 0, 0);
            // lane holds embeds e0..e0+3 of patch row `prow`
            const int e0 = ebase + et * 16 + lg * 4;
            f32x4 pv = *(const f32x4*)(posrow + e0);
            f32x4 o = acc + pv;
            *(f32x4*)(orow + e0) = o;
        }
    }
}

// ---------------------------------------------------------------------------
extern "C" void kernel_launch(void* const* d_in, const int* in_sizes, int n_in,
                              void* d_out, int out_size, void* d_ws, size_t ws_size,
                              hipStream_t stream) {
    const float* x   = (const float*)d_in[0];
    const float* W   = (const float*)d_in[1];
    const float* cls = (const float*)d_in[2];
    const float* pos = (const float*)d_in[3];
    float* out = (float*)d_out;

    hipLaunchKernelGGL(patch_embed_fused, dim3(BATCH), dim3(512), 0, stream,
                       x, W, cls, pos, out);
}

// Round 7
// 46.516 us; speedup vs baseline: 1.2676x; 1.2676x over previous
//
#include <hip/hip_runtime.h>

// ViT patch-embed, fused single kernel.
// out[b,0,e] = cls[e] + pos[0,e];  out[b,n+1,e] = sum_k patch[b,n,k]*W[e,k] + pos[n+1,e]
// B=1024, 64 patches of K=48 (padded to 64), E=768. Output 204.5 MB f32.
// Ledger: R4 NT stores -11.5us (never nt for streaming output). R6 swapped-operand
// 16-row-scatter stores -12us. R5 core (A=patches,B=W) = 46.8us at ~4.5 TB/s vs
// fill-kernel ceiling 6.9 TB/s with contiguous full-line stores.
// R7: LDS-transposed epilogue -- acc -> f32 LDS stage -> cooperative contiguous
// f32x4 stores (1024B/wave-instr, full 128B lines), pos fused in store pass.

#define BATCH   1024
#define EMBED   768
#define NPATCH  64
#define SEQ     65
#define OUTB    (SEQ * EMBED)   // 49920
#define LDSF    772             // f32 stage row stride (768 + 4 pad: 16B-aligned rows, 2-way banks)

typedef __attribute__((ext_vector_type(8))) short bf16x8;   // 8 bf16 (4 VGPRs)
typedef __attribute__((ext_vector_type(4))) float f32x4;    // MFMA acc / 16B ld-st

__device__ __forceinline__ short f2bf(float f) {
    union { float f; unsigned u; } v; v.f = f;
    unsigned r = v.u + 0x7FFFu + ((v.u >> 16) & 1u);   // RNE
    return (short)(r >> 16);
}

// ---------------------------------------------------------------------------
// One batch per block, 8 waves. Wave owns 96 embeds (6 N-tiles of 16).
// Compute core (identical to R5): A-frag = patch rows, B-frag = W cols.
//   v_mfma_f32_16x16x32_bf16: D lane -> col e (l&15), row n = (l>>4)*4 + reg.
// Epilogue: acc -> S[16][LDSF] f32 stage -> contiguous cooperative stores.
// ---------------------------------------------------------------------------
__global__ __launch_bounds__(512, 4) void patch_embed_fused(const float* __restrict__ x,
                                                            const float* __restrict__ W,
                                                            const float* __restrict__ cls,
                                                            const float* __restrict__ pos,
                                                            float* __restrict__ out) {
    __shared__ short A[64 * 64];      // 8 KB bf16 patches
    __shared__ float S[16 * LDSF];    // 49.4 KB f32 output stage

    const int tid  = threadIdx.x;
    const int lane = tid & 63;
    const int wave = tid >> 6;     // 0..7
    const int lr   = lane & 15;
    const int lg   = lane >> 4;    // 0..3
    const int ebase = wave * 96;
    const int b = blockIdx.x;

    // ---- cls row: out[b,0,:] = cls + pos[0,:]  (192 f32x4, threads 0..191) ----
    if (tid < 192) {
        f32x4 cv = ((const f32x4*)cls)[tid];
        f32x4 pv = ((const f32x4*)pos)[tid];
        ((f32x4*)out)[(size_t)b * (OUTB / 4) + tid] = cv + pv;
    }

    // ---- stage x[b] -> LDS bf16 patches [64][64], swizzled 16B chunks ----
    {
        const int row = tid >> 3;            // patch n = gr*8+gc
        const int kb  = tid & 7;             // 8-bf16 chunk within the 64-wide row
        short* dst = &A[row * 64 + ((kb ^ (row & 7)) * 8)];
        bf16x8 v = {0, 0, 0, 0, 0, 0, 0, 0};
        if (kb < 6) {   // k = c*16 + ph*4 + pw
            const int c   = kb >> 1;
            const int ph0 = (kb & 1) * 2;
            const int gr = row >> 3, gc = row & 7;
            const float* src = x + (size_t)b * 3072 + c * 1024 + (gr * 4 + ph0) * 32 + gc * 4;
            float4 u0 = *(const float4*)src;
            float4 u1 = *(const float4*)(src + 32);
            v[0] = f2bf(u0.x); v[1] = f2bf(u0.y); v[2] = f2bf(u0.z); v[3] = f2bf(u0.w);
            v[4] = f2bf(u1.x); v[5] = f2bf(u1.y); v[6] = f2bf(u1.z); v[7] = f2bf(u1.w);
        }
        *(bf16x8*)dst = v;
    }

    // ---- W fragments (B-operand) -> registers: bw[6][2], 48 VGPR ----
    bf16x8 bw[6][2];
    #pragma unroll
    for (int nt = 0; nt < 6; ++nt) {
        const float* wrow = W + (ebase + nt * 16 + lr) * 48;
        #pragma unroll
        for (int kk = 0; kk < 2; ++kk) {
            const int k0 = kk * 32 + lg * 8;
            bf16x8 f = {0, 0, 0, 0, 0, 0, 0, 0};
            if (k0 < 48) {
                float4 u0 = *(const float4*)(wrow + k0);
                float4 u1 = *(const float4*)(wrow + k0 + 4);
                f[0] = f2bf(u0.x); f[1] = f2bf(u0.y); f[2] = f2bf(u0.z); f[3] = f2bf(u0.w);
                f[4] = f2bf(u1.x); f[5] = f2bf(u1.y); f[6] = f2bf(u1.z); f[7] = f2bf(u1.w);
            }
            bw[nt][kk] = f;
        }
    }

    __syncthreads();

    // ---- per 16-patch M-tile: MFMA -> LDS stage -> contiguous stores ----
    const int srow = tid >> 5;         // 0..15: stage row this thread stores
    const int scol = (tid & 31) * 4;   // f32 col base (step 128 per j)
    #pragma unroll 1
    for (int mt = 0; mt < 4; ++mt) {
        const int arow = mt * 16 + lr;
        const int sw0  = ((0 * 4 + lg) ^ (arow & 7)) * 8;
        const int sw1  = ((1 * 4 + lg) ^ (arow & 7)) * 8;
        bf16x8 a0 = *(const bf16x8*)&A[arow * 64 + sw0];   // k 0..31
        bf16x8 a1 = *(const bf16x8*)&A[arow * 64 + sw1];   // k 32..63

        f32x4 acc[6];
        const f32x4 zero = {0.f, 0.f, 0.f, 0.f};
        #pragma unroll
        for (int nt = 0; nt < 6; ++nt)
            acc[nt] = __builtin_amdgcn_mfma_f32_16x16x32_bf16(a0, bw[nt][0], zero, 0, 0, 0);
        #pragma unroll
        for (int nt = 0; nt < 6; ++nt)
            acc[nt] = __builtin_amdgcn_mfma_f32_16x16x32_bf16(a1, bw[nt][1], acc[nt], 0, 0, 0);

        __syncthreads();   // WAR: previous tile's S reads complete before overwrite

        // acc -> stage: S[r = lg*4+j][e = ebase + nt*16 + lr]
        #pragma unroll
        for (int j = 0; j < 4; ++j) {
            float* sr = &S[(lg * 4 + j) * LDSF + ebase + lr];
            #pragma unroll
            for (int nt = 0; nt < 6; ++nt)
                sr[nt * 16] = acc[nt][j];
        }
        __syncthreads();   // stage complete

        // cooperative contiguous store: thread -> row srow, cols scol + j*128
        const size_t obase = (size_t)b * OUTB + (size_t)(mt * 16 + 1) * EMBED;
        const float* prow = pos + (size_t)(mt * 16 + 1) * EMBED;
        #pragma unroll
        for (int j = 0; j < 6; ++j) {
            const int c = scol + j * 128;
            f32x4 v  = *(const f32x4*)&S[srow * LDSF + c];
            f32x4 pv = *(const f32x4*)(prow + (size_t)srow * EMBED + c);
            *(f32x4*)(out + obase + (size_t)srow * EMBED + c) = v + pv;
        }
    }
}

// ---------------------------------------------------------------------------
extern "C" void kernel_launch(void* const* d_in, const int* in_sizes, int n_in,
                              void* d_out, int out_size, void* d_ws, size_t ws_size,
                              hipStream_t stream) {
    const float* x   = (const float*)d_in[0];
    const float* W   = (const float*)d_in[1];
    const float* cls = (const float*)d_in[2];
    const float* pos = (const float*)d_in[3];
    float* out = (float*)d_out;

    hipLaunchKernelGGL(patch_embed_fused, dim3(BATCH), dim3(512), 0, stream,
                       x, W, cls, pos, out);
}